// Round 19
// baseline (84.996 us; speedup 1.0000x reference)
//
#include <hip/hip_runtime.h>
#include <stdint.h>

typedef float  f32x4 __attribute__((ext_vector_type(4)));
typedef short  s16x8 __attribute__((ext_vector_type(8)));
typedef unsigned short u16;

#define KK 32768   /* NN*DD */

__device__ __forceinline__ u16 f2bf_rn(float f) {
  uint32_t u = __float_as_uint(f);
  u += 0x7fffu + ((u >> 16) & 1u);
  return (u16)(u >> 16);
}
__device__ __forceinline__ float bf2f(u16 h) {
  return __uint_as_float(((uint32_t)h) << 16);
}

// global -> LDS direct DMA, 16B per lane. LDS dest = wave-uniform base + lane*16.
__device__ __forceinline__ void gload_lds16(const void* g, void* l) {
  __builtin_amdgcn_global_load_lds(
      (const __attribute__((address_space(1))) uint32_t*)g,
      (__attribute__((address_space(3))) uint32_t*)l, 16, 0, 0);
}

// ---------------------------------------------------------------------------
// Kernel A: g_swz[b][c][k] = x[b,s,c]*W[d,c] with k pre-XOR-swizzled so the
// GEMM's linear global_load_lds staging yields a bank-conflict-free LDS tile:
// value stored at output k holds source k ^ ((c&7)<<3)  (within 64-k blocks).
// Split into bf16 hi/lo planes.  [identical to round-7/17/18 champion]
// ---------------------------------------------------------------------------
__global__ void build_g(const float* __restrict__ x, const float* __restrict__ W,
                        u16* __restrict__ ghi, u16* __restrict__ glo) {
  int t   = blockIdx.x * 256 + threadIdx.x;
  int k0o = (t & 4095) << 3;       // output k, multiple of 8
  int c   = (t >> 12) & 63;
  int b   = t >> 18;
  int k0s = k0o ^ ((c & 7) << 3);  // source k (aligned-8 block within same 64-blk)
  int s   = k0s >> 5;
  int d0  = k0s & 31;              // in {0,8,16,24}; +7 stays in the same s
  float xv = x[(((b << 10) + s) << 6) + c];
  s16x8 vh, vl;
#pragma unroll
  for (int i = 0; i < 8; ++i) {
    float g = xv * W[((d0 + i) << 6) + c];
    u16 h = f2bf_rn(g);
    vh[i] = (short)h;
    vl[i] = (short)f2bf_rn(g - bf2f(h));
  }
  size_t off = (((size_t)((b << 6) + c)) << 15) + (size_t)k0o;
  *reinterpret_cast<s16x8*>(ghi + off) = vh;
  *reinterpret_cast<s16x8*>(glo + off) = vl;
}

// ---------------------------------------------------------------------------
// Kernel B: split-K GEMM, BK=64 double-buffered LDS with counted-vmcnt
// schedule [loop body byte-identical to round-7/17/18 champion]: per iter
// {lgkmcnt0; bar; STAGE(t+1); vmcnt(8); bar; compute} — prefetch stays in
// flight across barriers, never drained to 0 mid-loop.
// LDS map (64KB): A[q] at q*16KB; BH[q] at 32KB+q*8KB; BL[q] at 48KB+q*8KB.
// ---------------------------------------------------------------------------
#define MFMA16(A_, B_, C_) __builtin_amdgcn_mfma_f32_16x16x32_bf16((A_), (B_), (C_), 0, 0, 0)

__global__ __launch_bounds__(256, 2) void gemm_split(
    const float* __restrict__ kb, const u16* __restrict__ ghi,
    const u16* __restrict__ glo, float* __restrict__ part,
    int Sk, int Kc) {
  __shared__ unsigned char lds[65536];

  const int tid = threadIdx.x;
  const int w  = tid >> 6;
  const int l  = tid & 63;
  const int lr = l & 15;
  const int lk = l >> 4;
  const int mt = blockIdx.x;
  const int ks = blockIdx.y;
  const int b  = blockIdx.z;

  const size_t k0 = (size_t)ks * (size_t)Kc;
  const int nt = Kc >> 6;          // 64-k steps

  // ---- staging sources (per-thread global addr, wave-uniform LDS base) ----
  const float* asrc[4]; int aldsw[4];
#pragma unroll
  for (int i = 0; i < 4; ++i) {
    int P   = i * 4096 + tid * 16;       // linear byte pos in 16KB A-tile
    int row = P >> 8;                    // 0..63 (256B rows)
    int cs  = P & 255;                   // stored col byte
    int csrc = cs ^ ((row & 7) << 4);    // pre-swizzled source col
    asrc[i]  = kb + (((size_t)((b << 10) + (mt << 6) + row)) << 15) + k0 + (csrc >> 2);
    aldsw[i] = i * 4096 + w * 1024;      // wave base; HW adds lane*16
  }
  const u16* bsrcH[2]; const u16* bsrcL[2]; int bldsw[2];
#pragma unroll
  for (int i = 0; i < 2; ++i) {
    int P  = i * 4096 + tid * 16;        // linear byte pos in 8KB B-tile
    int c  = P >> 7;                     // 0..63 (128B rows)
    int kbyte = P & 127;
    size_t go = (((size_t)((b << 6) + c)) << 15) + k0 + (size_t)(kbyte >> 1);
    bsrcH[i] = ghi + go;
    bsrcL[i] = glo + go;
    bldsw[i] = i * 4096 + w * 1024;
  }

  const int arow = (w << 4) + lr;
  const int abase = arow << 8;           // arow*256
  const int aswz  = (arow & 7) << 4;
  const int bswz  = (lr & 7) << 4;

  f32x4 acc[4] = {f32x4{0,0,0,0}, f32x4{0,0,0,0}, f32x4{0,0,0,0}, f32x4{0,0,0,0}};

  auto STAGE = [&](int t, int q) {
    size_t tk = (size_t)t << 6;          // 64 elements per step
#pragma unroll
    for (int i = 0; i < 4; ++i)
      gload_lds16(asrc[i] + tk, lds + q * 16384 + aldsw[i]);
#pragma unroll
    for (int i = 0; i < 2; ++i) {
      gload_lds16(bsrcH[i] + tk, lds + 32768 + q * 8192 + bldsw[i]);
      gload_lds16(bsrcL[i] + tk, lds + 49152 + q * 8192 + bldsw[i]);
    }
  };

  STAGE(0, 0);

  int q = 0;
  for (int t = 0; t < nt; ++t, q ^= 1) {
    // B1: everyone finished reading buffer q^1 (previous iter's compute)
    // before STAGE overwrites it. lgkmcnt already 0 (MFMAs consumed reads).
    asm volatile("s_waitcnt lgkmcnt(0)" ::: "memory");
    __builtin_amdgcn_sched_barrier(0);
    __builtin_amdgcn_s_barrier();

    if (t + 1 < nt) {
      STAGE(t + 1, q ^ 1);               // 8 loads into q^1, stay in flight
      asm volatile("s_waitcnt vmcnt(8)" ::: "memory");  // tile-t landed (mine)
    } else {
      asm volatile("s_waitcnt vmcnt(0)" ::: "memory");
    }
    __builtin_amdgcn_sched_barrier(0);
    __builtin_amdgcn_s_barrier();        // B2: all waves' tile-t landed

    const unsigned char* LA = lds + q * 16384;
    const unsigned char* LH = lds + 32768 + q * 8192;
    const unsigned char* LL = lds + 49152 + q * 8192;

#pragma unroll
    for (int kb2 = 0; kb2 < 2; ++kb2) {
      int ac = (kb2 << 7) + (lk << 5);   // col byte of frag (fp32)
      f32x4 a0 = *reinterpret_cast<const f32x4*>(LA + abase + ( ac        ^ aswz));
      f32x4 a1 = *reinterpret_cast<const f32x4*>(LA + abase + ((ac + 16)  ^ aswz));
      s16x8 ah, al;
#pragma unroll
      for (int i = 0; i < 8; ++i) {
        float f = (i < 4) ? a0[i] : a1[i - 4];
        uint32_t u = __float_as_uint(f);
        ah[i] = (short)(u16)(u >> 16);
        al[i] = (short)f2bf_rn(f - __uint_as_float(u & 0xffff0000u));
      }
      int bko = (kb2 << 6) + (lk << 4);  // k byte of frag (bf16)
#pragma unroll
      for (int ct = 0; ct < 4; ++ct) {
        int cc = (ct << 4) + lr;
        int bo = (cc << 7) + (bko ^ bswz);
        s16x8 bh = *reinterpret_cast<const s16x8*>(LH + bo);
        s16x8 bl = *reinterpret_cast<const s16x8*>(LL + bo);
        acc[ct] = MFMA16(ah, bh, acc[ct]);
        acc[ct] = MFMA16(al, bh, acc[ct]);
        acc[ct] = MFMA16(ah, bl, acc[ct]);
      }
    }
  }

  // partials: part[((b*Sk + ks)*1024 + r)*64 + c]
  float* pb = part + (((size_t)(b * Sk + ks)) << 16);
#pragma unroll
  for (int ct = 0; ct < 4; ++ct) {
#pragma unroll
    for (int i = 0; i < 4; ++i) {
      int rr = (mt << 6) + (w << 4) + (lk << 2) + i;
      int cc = (ct << 4) + lr;
      pb[((size_t)rr << 6) + cc] = acc[ct][i];
    }
  }
}

// ---------------------------------------------------------------------------
// Kernel C: per (b,r): reduce Sk partials + conv_bias -> LayerNorm -> MLP.
// ---------------------------------------------------------------------------
__device__ __forceinline__ float gelu_tanh(float v) {
  float u = 0.7978845608028654f * (v + 0.044715f * v * v * v);
  float e = __expf(2.0f * u);
  float th = 1.0f - 2.0f / (e + 1.0f);
  return 0.5f * v * (1.0f + th);
}

__global__ __launch_bounds__(256) void epilogue(
    const float* __restrict__ part, const float* __restrict__ conv_bias,
    const float* __restrict__ ln_scale, const float* __restrict__ ln_bias,
    const float* __restrict__ W1, const float* __restrict__ b1,
    const float* __restrict__ W2, const float* __restrict__ b2,
    float* __restrict__ out, int Sk) {
  __shared__ float red[4][64];
  __shared__ float nbuf[64];
  __shared__ float hbuf[256];

  const int tid = threadIdx.x;
  const int b = blockIdx.x >> 10;
  const int r = blockIdx.x & 1023;
  const int c = tid & 63;
  const int q = tid >> 6;

  float s = 0.0f;
  for (int ks = q; ks < Sk; ks += 4)
    s += part[(((size_t)(b * Sk + ks)) << 16) + ((size_t)r << 6) + c];
  red[q][c] = s;
  __syncthreads();

  if (q == 0) {
    float a = red[0][c] + red[1][c] + red[2][c] + red[3][c] + conv_bias[c];
    float sum = a;
#pragma unroll
    for (int off = 32; off >= 1; off >>= 1) sum += __shfl_xor(sum, off);
    float mu = sum * (1.0f / 64.0f);
    float d = a - mu;
    float ss = d * d;
#pragma unroll
    for (int off = 32; off >= 1; off >>= 1) ss += __shfl_xor(ss, off);
    float var = ss * (1.0f / 64.0f);
    nbuf[c] = d * rsqrtf(var + 1e-6f) * ln_scale[c] + ln_bias[c];
  }
  __syncthreads();

  {
    float acc = b1[tid];
#pragma unroll 8
    for (int cc = 0; cc < 64; ++cc) acc += nbuf[cc] * W1[(cc << 8) + tid];
    hbuf[tid] = gelu_tanh(acc);
  }
  __syncthreads();

  {
    float po = 0.0f;
#pragma unroll 8
    for (int jj = 0; jj < 64; ++jj) {
      int j = (q << 6) + jj;
      po += hbuf[j] * W2[(j << 6) + c];
    }
    red[q][c] = po;
  }
  __syncthreads();
  if (tid < 64) {
    float o = red[0][c] + red[1][c] + red[2][c] + red[3][c] + b2[c];
    out[(((size_t)(b << 10) + r) << 6) + c] = o;
  }
}

// ---------------------------------------------------------------------------
extern "C" void kernel_launch(void* const* d_in, const int* in_sizes, int n_in,
                              void* d_out, int out_size, void* d_ws, size_t ws_size,
                              hipStream_t stream) {
  const float* x         = (const float*)d_in[0];
  const float* kb        = (const float*)d_in[1];
  const float* kernel_W  = (const float*)d_in[2];
  const float* conv_bias = (const float*)d_in[3];
  const float* ln_scale  = (const float*)d_in[4];
  const float* ln_bias   = (const float*)d_in[5];
  const float* W1        = (const float*)d_in[6];
  const float* b1        = (const float*)d_in[7];
  const float* W2        = (const float*)d_in[8];
  const float* b2        = (const float*)d_in[9];
  float* out = (float*)d_out;

  char* wsb = (char*)d_ws;
  u16* ghi = (u16*)wsb;                               // 8,388,608 B
  u16* glo = (u16*)(wsb + 8388608);                   // 8,388,608 B
  float* part = (float*)(wsb + 16777216);             // Sk * 524,288 B

  // Sk=8: halves epilogue part-traffic vs round-18 (Sk=16); 256 WGs = one
  // residency round of 1 WG/CU (r8 showed 1-WG/CU GEMM runs at the same
  // plateau). Loop body byte-identical; nt doubles to 64.
  int Sk = 8;
  while (Sk > 1 && 16777216ull + (size_t)Sk * 524288ull > ws_size) Sk >>= 1;
  int Kc = KK / Sk;

  build_g<<<2048, 256, 0, stream>>>(x, kernel_W, ghi, glo);
  gemm_split<<<dim3(16, Sk, 2), 256, 0, stream>>>(kb, ghi, glo, part, Sk, Kc);
  epilogue<<<dim3(2048), 256, 0, stream>>>(part, conv_bias, ln_scale, ln_bias,
                                           W1, b1, W2, b2, out, Sk);
}

// Round 20
// 84.498 us; speedup vs baseline: 1.0059x; 1.0059x over previous
//
#include <hip/hip_runtime.h>
#include <stdint.h>

typedef float  f32x4 __attribute__((ext_vector_type(4)));
typedef short  s16x8 __attribute__((ext_vector_type(8)));
typedef unsigned short u16;

#define KK 32768   /* NN*DD */

__device__ __forceinline__ u16 f2bf_rn(float f) {
  uint32_t u = __float_as_uint(f);
  u += 0x7fffu + ((u >> 16) & 1u);
  return (u16)(u >> 16);
}
__device__ __forceinline__ float bf2f(u16 h) {
  return __uint_as_float(((uint32_t)h) << 16);
}

// global -> LDS direct DMA, 16B per lane. LDS dest = wave-uniform base + lane*16.
__device__ __forceinline__ void gload_lds16(const void* g, void* l) {
  __builtin_amdgcn_global_load_lds(
      (const __attribute__((address_space(1))) uint32_t*)g,
      (__attribute__((address_space(3))) uint32_t*)l, 16, 0, 0);
}

// ---------------------------------------------------------------------------
// Kernel A: g_swz[b][c][k] = x[b,s,c]*W[d,c] with k pre-XOR-swizzled so the
// GEMM's linear global_load_lds staging yields a bank-conflict-free LDS tile:
// value stored at output k holds source k ^ ((c&7)<<3)  (within 64-k blocks).
// Split into bf16 hi/lo planes.
// ---------------------------------------------------------------------------
__global__ void build_g(const float* __restrict__ x, const float* __restrict__ W,
                        u16* __restrict__ ghi, u16* __restrict__ glo) {
  int t   = blockIdx.x * 256 + threadIdx.x;
  int k0o = (t & 4095) << 3;       // output k, multiple of 8
  int c   = (t >> 12) & 63;
  int b   = t >> 18;
  int k0s = k0o ^ ((c & 7) << 3);  // source k (aligned-8 block within same 64-blk)
  int s   = k0s >> 5;
  int d0  = k0s & 31;              // in {0,8,16,24}; +7 stays in the same s
  float xv = x[(((b << 10) + s) << 6) + c];
  s16x8 vh, vl;
#pragma unroll
  for (int i = 0; i < 8; ++i) {
    float g = xv * W[((d0 + i) << 6) + c];
    u16 h = f2bf_rn(g);
    vh[i] = (short)h;
    vl[i] = (short)f2bf_rn(g - bf2f(h));
  }
  size_t off = (((size_t)((b << 6) + c)) << 15) + (size_t)k0o;
  *reinterpret_cast<s16x8*>(ghi + off) = vh;
  *reinterpret_cast<s16x8*>(glo + off) = vl;
}

// ---------------------------------------------------------------------------
// Kernel B: split-K GEMM, BK=64 double-buffered LDS with counted-vmcnt
// schedule [round-7 champion loop body]: per iter
// {lgkmcnt0; bar; STAGE(t+1); vmcnt(8); bar; compute} — prefetch stays in
// flight across barriers, never drained to 0 mid-loop.
// LDS map (64KB): A[q] at q*16KB; BH[q] at 32KB+q*8KB; BL[q] at 48KB+q*8KB.
// ---------------------------------------------------------------------------
#define MFMA16(A_, B_, C_) __builtin_amdgcn_mfma_f32_16x16x32_bf16((A_), (B_), (C_), 0, 0, 0)

__global__ __launch_bounds__(256, 2) void gemm_split(
    const float* __restrict__ kb, const u16* __restrict__ ghi,
    const u16* __restrict__ glo, float* __restrict__ part,
    int Sk, int Kc) {
  __shared__ unsigned char lds[65536];

  const int tid = threadIdx.x;
  const int w  = tid >> 6;
  const int l  = tid & 63;
  const int lr = l & 15;
  const int lk = l >> 4;
  const int mt = blockIdx.x;
  const int ks = blockIdx.y;
  const int b  = blockIdx.z;

  const size_t k0 = (size_t)ks * (size_t)Kc;
  const int nt = Kc >> 6;          // 64-k steps

  // ---- staging sources (per-thread global addr, wave-uniform LDS base) ----
  const float* asrc[4]; int aldsw[4];
#pragma unroll
  for (int i = 0; i < 4; ++i) {
    int P   = i * 4096 + tid * 16;       // linear byte pos in 16KB A-tile
    int row = P >> 8;                    // 0..63 (256B rows)
    int cs  = P & 255;                   // stored col byte
    int csrc = cs ^ ((row & 7) << 4);    // pre-swizzled source col
    asrc[i]  = kb + (((size_t)((b << 10) + (mt << 6) + row)) << 15) + k0 + (csrc >> 2);
    aldsw[i] = i * 4096 + w * 1024;      // wave base; HW adds lane*16
  }
  const u16* bsrcH[2]; const u16* bsrcL[2]; int bldsw[2];
#pragma unroll
  for (int i = 0; i < 2; ++i) {
    int P  = i * 4096 + tid * 16;        // linear byte pos in 8KB B-tile
    int c  = P >> 7;                     // 0..63 (128B rows)
    int kbyte = P & 127;
    size_t go = (((size_t)((b << 6) + c)) << 15) + k0 + (size_t)(kbyte >> 1);
    bsrcH[i] = ghi + go;
    bsrcL[i] = glo + go;
    bldsw[i] = i * 4096 + w * 1024;
  }

  const int arow = (w << 4) + lr;
  const int abase = arow << 8;           // arow*256
  const int aswz  = (arow & 7) << 4;
  const int bswz  = (lr & 7) << 4;

  f32x4 acc[4] = {f32x4{0,0,0,0}, f32x4{0,0,0,0}, f32x4{0,0,0,0}, f32x4{0,0,0,0}};

  auto STAGE = [&](int t, int q) {
    size_t tk = (size_t)t << 6;          // 64 elements per step
#pragma unroll
    for (int i = 0; i < 4; ++i)
      gload_lds16(asrc[i] + tk, lds + q * 16384 + aldsw[i]);
#pragma unroll
    for (int i = 0; i < 2; ++i) {
      gload_lds16(bsrcH[i] + tk, lds + 32768 + q * 8192 + bldsw[i]);
      gload_lds16(bsrcL[i] + tk, lds + 49152 + q * 8192 + bldsw[i]);
    }
  };

  STAGE(0, 0);

  int q = 0;
  for (int t = 0; t < nt; ++t, q ^= 1) {
    // B1: everyone finished reading buffer q^1 (previous iter's compute)
    // before STAGE overwrites it. lgkmcnt already 0 (MFMAs consumed reads).
    asm volatile("s_waitcnt lgkmcnt(0)" ::: "memory");
    __builtin_amdgcn_sched_barrier(0);
    __builtin_amdgcn_s_barrier();

    if (t + 1 < nt) {
      STAGE(t + 1, q ^ 1);               // 8 loads into q^1, stay in flight
      asm volatile("s_waitcnt vmcnt(8)" ::: "memory");  // tile-t landed (mine)
    } else {
      asm volatile("s_waitcnt vmcnt(0)" ::: "memory");
    }
    __builtin_amdgcn_sched_barrier(0);
    __builtin_amdgcn_s_barrier();        // B2: all waves' tile-t landed

    const unsigned char* LA = lds + q * 16384;
    const unsigned char* LH = lds + 32768 + q * 8192;
    const unsigned char* LL = lds + 49152 + q * 8192;

#pragma unroll
    for (int kb2 = 0; kb2 < 2; ++kb2) {
      int ac = (kb2 << 7) + (lk << 5);   // col byte of frag (fp32)
      f32x4 a0 = *reinterpret_cast<const f32x4*>(LA + abase + ( ac        ^ aswz));
      f32x4 a1 = *reinterpret_cast<const f32x4*>(LA + abase + ((ac + 16)  ^ aswz));
      s16x8 ah, al;
#pragma unroll
      for (int i = 0; i < 8; ++i) {
        float f = (i < 4) ? a0[i] : a1[i - 4];
        uint32_t u = __float_as_uint(f);
        ah[i] = (short)(u16)(u >> 16);
        al[i] = (short)f2bf_rn(f - __uint_as_float(u & 0xffff0000u));
      }
      int bko = (kb2 << 6) + (lk << 4);  // k byte of frag (bf16)
#pragma unroll
      for (int ct = 0; ct < 4; ++ct) {
        int cc = (ct << 4) + lr;
        int bo = (cc << 7) + (bko ^ bswz);
        s16x8 bh = *reinterpret_cast<const s16x8*>(LH + bo);
        s16x8 bl = *reinterpret_cast<const s16x8*>(LL + bo);
        acc[ct] = MFMA16(ah, bh, acc[ct]);
        acc[ct] = MFMA16(al, bh, acc[ct]);
        acc[ct] = MFMA16(ah, bl, acc[ct]);
      }
    }
  }

  // partials: part[((b*Sk + ks)*1024 + r)*64 + c]
  float* pb = part + (((size_t)(b * Sk + ks)) << 16);
#pragma unroll
  for (int ct = 0; ct < 4; ++ct) {
#pragma unroll
    for (int i = 0; i < 4; ++i) {
      int rr = (mt << 6) + (w << 4) + (lk << 2) + i;
      int cc = (ct << 4) + lr;
      pb[((size_t)rr << 6) + cc] = acc[ct][i];
    }
  }
}

// ---------------------------------------------------------------------------
// Kernel C: per (b,r): reduce Sk partials + conv_bias -> LayerNorm -> MLP.
// ---------------------------------------------------------------------------
__device__ __forceinline__ float gelu_tanh(float v) {
  float u = 0.7978845608028654f * (v + 0.044715f * v * v * v);
  float e = __expf(2.0f * u);
  float th = 1.0f - 2.0f / (e + 1.0f);
  return 0.5f * v * (1.0f + th);
}

__global__ __launch_bounds__(256) void epilogue(
    const float* __restrict__ part, const float* __restrict__ conv_bias,
    const float* __restrict__ ln_scale, const float* __restrict__ ln_bias,
    const float* __restrict__ W1, const float* __restrict__ b1,
    const float* __restrict__ W2, const float* __restrict__ b2,
    float* __restrict__ out, int Sk) {
  __shared__ float red[4][64];
  __shared__ float nbuf[64];
  __shared__ float hbuf[256];

  const int tid = threadIdx.x;
  const int b = blockIdx.x >> 10;
  const int r = blockIdx.x & 1023;
  const int c = tid & 63;
  const int q = tid >> 6;

  float s = 0.0f;
  for (int ks = q; ks < Sk; ks += 4)
    s += part[(((size_t)(b * Sk + ks)) << 16) + ((size_t)r << 6) + c];
  red[q][c] = s;
  __syncthreads();

  if (q == 0) {
    float a = red[0][c] + red[1][c] + red[2][c] + red[3][c] + conv_bias[c];
    float sum = a;
#pragma unroll
    for (int off = 32; off >= 1; off >>= 1) sum += __shfl_xor(sum, off);
    float mu = sum * (1.0f / 64.0f);
    float d = a - mu;
    float ss = d * d;
#pragma unroll
    for (int off = 32; off >= 1; off >>= 1) ss += __shfl_xor(ss, off);
    float var = ss * (1.0f / 64.0f);
    nbuf[c] = d * rsqrtf(var + 1e-6f) * ln_scale[c] + ln_bias[c];
  }
  __syncthreads();

  {
    float acc = b1[tid];
#pragma unroll 8
    for (int cc = 0; cc < 64; ++cc) acc += nbuf[cc] * W1[(cc << 8) + tid];
    hbuf[tid] = gelu_tanh(acc);
  }
  __syncthreads();

  {
    float po = 0.0f;
#pragma unroll 8
    for (int jj = 0; jj < 64; ++jj) {
      int j = (q << 6) + jj;
      po += hbuf[j] * W2[(j << 6) + c];
    }
    red[q][c] = po;
  }
  __syncthreads();
  if (tid < 64) {
    float o = red[0][c] + red[1][c] + red[2][c] + red[3][c] + b2[c];
    out[(((size_t)(b << 10) + r) << 6) + c] = o;
  }
}

// ---------------------------------------------------------------------------
extern "C" void kernel_launch(void* const* d_in, const int* in_sizes, int n_in,
                              void* d_out, int out_size, void* d_ws, size_t ws_size,
                              hipStream_t stream) {
  const float* x         = (const float*)d_in[0];
  const float* kb        = (const float*)d_in[1];
  const float* kernel_W  = (const float*)d_in[2];
  const float* conv_bias = (const float*)d_in[3];
  const float* ln_scale  = (const float*)d_in[4];
  const float* ln_bias   = (const float*)d_in[5];
  const float* W1        = (const float*)d_in[6];
  const float* b1        = (const float*)d_in[7];
  const float* W2        = (const float*)d_in[8];
  const float* b2        = (const float*)d_in[9];
  float* out = (float*)d_out;

  char* wsb = (char*)d_ws;
  u16* ghi = (u16*)wsb;                               // 8,388,608 B
  u16* glo = (u16*)(wsb + 8388608);                   // 8,388,608 B
  float* part = (float*)(wsb + 16777216);             // Sk * 524,288 B

  // FINAL CHAMPION (round 18): Sk=16 — measured optimum of the split-K
  // sweep (Sk=64: 93.0us, 32: 88.6, 16: 84.7, 8: 85.0). 512 WGs = one
  // residency round of 2 WGs/CU; part round-trip 16.8MB.
  int Sk = 16;
  while (Sk > 1 && 16777216ull + (size_t)Sk * 524288ull > ws_size) Sk >>= 1;
  int Kc = KK / Sk;

  build_g<<<2048, 256, 0, stream>>>(x, kernel_W, ghi, glo);
  gemm_split<<<dim3(16, Sk, 2), 256, 0, stream>>>(kb, ghi, glo, part, Sk, Kc);
  epilogue<<<dim3(2048), 256, 0, stream>>>(part, conv_bias, ln_scale, ln_bias,
                                           W1, b1, W2, b2, out, Sk);
}